// Round 1
// baseline (69.982 us; speedup 1.0000x reference)
//
#include <hip/hip_runtime.h>

#define NPGL 256     // nodes per graph
#define EPGL 2048    // edges per graph
#define HIDD 64
#define KKEEP 128
#define NTH 512

// float offset of float4-chunk c (0..15) of row n in the swizzled LDS tile
__device__ __forceinline__ int swz(int n, int c) {
  return (n << 6) + (((c ^ n) & 15) << 2);
}

__global__ void __launch_bounds__(NTH)
asap_fused(const float* __restrict__ x, const int* __restrict__ ei,
           const float* __restrict__ W1, const float* __restrict__ b1,
           const float* __restrict__ linW, const float* __restrict__ linb,
           const float* __restrict__ attW, const float* __restrict__ attb,
           const float* __restrict__ le1W, const float* __restrict__ le1b,
           const float* __restrict__ le2W,
           const float* __restrict__ le3W, const float* __restrict__ le3b,
           const float* __restrict__ W2, const float* __restrict__ b2,
           float* __restrict__ out, int Etot)
{
  const int g = blockIdx.x;
  const int tid = threadIdx.x;

  __shared__ __align__(16) float buf[NPGL * HIDD];   // 64KB: h -> h1 -> xnew
  __shared__ __align__(16) float w1s[HIDD * HIDD];   // 16KB: W1, later masks
  __shared__ unsigned short csrc[EPGL];              // 4KB CSR src (by dst)
  __shared__ int rowst[NPGL + 1];
  __shared__ int cnt[NPGL];
  __shared__ float dinv_[NPGL];                      // later: c3 per node
  __shared__ float sA[NPGL], sB[NPGL];               // later: a, bb per node
  __shared__ float eself[NPGL];
  __shared__ float rsf[NPGL];                        // recip softmax sum -> fitness
  __shared__ __align__(16) float esc[EPGL];          // 8KB: partials / exp scores
  __shared__ float u_[HIDD];
  __shared__ float wsum[HIDD];
  __shared__ float c0s;
  __shared__ int kcount;

  // aliases into w1s (W1 dead after phase 1)
  unsigned long long* Imask = (unsigned long long*)w1s;           // [256*4]
  unsigned long long* Rmask = ((unsigned long long*)w1s) + 1024;  // [128*4]
  unsigned long long* conn  = ((unsigned long long*)w1s) + 1536;  // [128*2]
  int*   kept = (int*)(w1s + 3584);                               // [128]
  float* d2A  = w1s + 3712;                                       // [128]
  float* cA   = w1s + 3840;                                       // [128]

  const int ebase = g * EPGL;
  const int nbase = g * NPGL;

  // ---------------- Phase 0: CSR build (by dst) ----------------
  if (tid < NPGL) cnt[tid] = 0;
  if (tid == 0) kcount = 0;
  __syncthreads();

  int es[4], ed[4];
#pragma unroll
  for (int i = 0; i < 4; ++i) {
    const int e = tid + i * NTH;
    es[i] = ei[ebase + e] - nbase;
    ed[i] = ei[Etot + ebase + e] - nbase;
    atomicAdd(&cnt[ed[i]], 1);
  }
  __syncthreads();

  if (tid < NPGL) {               // lockstep prefix sum (broadcast reads)
    int acc = 0;
    for (int m = 0; m <= tid; ++m) acc += cnt[m];
    rowst[tid + 1] = acc;
  }
  if (tid == 0) rowst[0] = 0;
  __syncthreads();

  if (tid < NPGL) cnt[tid] = rowst[tid];
  __syncthreads();

#pragma unroll
  for (int i = 0; i < 4; ++i) {
    const int p = atomicAdd(&cnt[ed[i]], 1);
    csrc[p] = (unsigned short)es[i];
  }
  if (tid < NPGL) {
    const int len = rowst[tid + 1] - rowst[tid];
    dinv_[tid] = rsqrtf((float)len + 1.0f);       // conv1: +1 self loop
  }
  if (tid < HIDD) {                               // u = lin_W @ attW[:64]
    float a = 0.f;
    for (int f = 0; f < HIDD; ++f) a += linW[tid * HIDD + f] * attW[f];
    u_[tid] = a;
  }
  if (tid == 0) {
    float a = 0.f;
    for (int f = 0; f < HIDD; ++f) a += linb[f] * attW[f];
    c0s = a + attb[0];
  }
  for (int i = tid; i < HIDD * HIDD; i += NTH) w1s[i] = W1[i];
  __syncthreads();

  // ---------------- Phase 1: h = x @ W1 -> buf ----------------
  {
    const int n2 = tid >> 2;           // 0..127 node pair
    const int qq = tid & 3;            // 16-feature block
    const int r0 = n2 * 2, r1 = r0 + 1;
    const float4* xg0 = (const float4*)(x + (size_t)(nbase + r0) * HIDD);
    const float4* xg1 = (const float4*)(x + (size_t)(nbase + r1) * HIDD);
    float4 a0[4], a1[4];
#pragma unroll
    for (int c = 0; c < 4; ++c) {
      a0[c] = make_float4(0.f, 0.f, 0.f, 0.f);
      a1[c] = make_float4(0.f, 0.f, 0.f, 0.f);
    }
    for (int pass = 0; pass < 4; ++pass) {
      float4 xa[4], xb[4];
#pragma unroll
      for (int c = 0; c < 4; ++c) { xa[c] = xg0[pass * 4 + c]; xb[c] = xg1[pass * 4 + c]; }
#pragma unroll
      for (int kk = 0; kk < 16; ++kk) {
        const int k = pass * 16 + kk;
        const float xv0 = ((const float*)xa)[kk];
        const float xv1 = ((const float*)xb)[kk];
        const float4* wr = (const float4*)&w1s[k * HIDD + qq * 16];
#pragma unroll
        for (int c = 0; c < 4; ++c) {
          const float4 w = wr[c];
          a0[c].x += xv0 * w.x; a0[c].y += xv0 * w.y; a0[c].z += xv0 * w.z; a0[c].w += xv0 * w.w;
          a1[c].x += xv1 * w.x; a1[c].y += xv1 * w.y; a1[c].z += xv1 * w.z; a1[c].w += xv1 * w.w;
        }
      }
    }
#pragma unroll
    for (int c = 0; c < 4; ++c) {
      *(float4*)&buf[swz(r0, qq * 4 + c)] = a0[c];
      *(float4*)&buf[swz(r1, qq * 4 + c)] = a1[c];
    }
  }
  __syncthreads();

  // ---------------- Phase 2: h1 = relu(GCN agg) (in-place) ----------------
  {
    const int d = tid >> 1, hh = tid & 1;
    const int cb = hh * 8, fb = hh * 32;
    const float dd = dinv_[d];
    const float sc_ = dd * dd;
    float4 acc[8];
#pragma unroll
    for (int c = 0; c < 8; ++c) {
      const float4 hv = *(const float4*)&buf[swz(d, cb + c)];
      const float4 bv = *(const float4*)&b1[fb + c * 4];
      acc[c].x = hv.x * sc_ + bv.x; acc[c].y = hv.y * sc_ + bv.y;
      acc[c].z = hv.z * sc_ + bv.z; acc[c].w = hv.w * sc_ + bv.w;
    }
    const int s0 = rowst[d], s1 = rowst[d + 1];
    for (int it = s0; it < s1; ++it) {
      const int s = csrc[it];
      const float cf = dinv_[s] * dd;
#pragma unroll
      for (int c = 0; c < 8; ++c) {
        const float4 hv = *(const float4*)&buf[swz(s, cb + c)];
        acc[c].x += cf * hv.x; acc[c].y += cf * hv.y;
        acc[c].z += cf * hv.z; acc[c].w += cf * hv.w;
      }
    }
#pragma unroll
    for (int c = 0; c < 8; ++c) {
      acc[c].x = fmaxf(acc[c].x, 0.f); acc[c].y = fmaxf(acc[c].y, 0.f);
      acc[c].z = fmaxf(acc[c].z, 0.f); acc[c].w = fmaxf(acc[c].w, 0.f);
    }
    __syncthreads();
#pragma unroll
    for (int c = 0; c < 8; ++c) *(float4*)&buf[swz(d, cb + c)] = acc[c];
  }
  __syncthreads();

  // ---------------- Phase 3: sA (via segment-max dot u), sB ----------------
  {
    const int d = tid >> 1, hh = tid & 1;
    const int cb = hh * 8;
    float4 mx[8];
    float sBp = 0.f;
#pragma unroll
    for (int c = 0; c < 8; ++c) {
      const float4 hv = *(const float4*)&buf[swz(d, cb + c)];
      mx[c] = hv;
      const float4 aw = *(const float4*)&attW[HIDD + hh * 32 + c * 4];
      sBp += hv.x * aw.x + hv.y * aw.y + hv.z * aw.z + hv.w * aw.w;
    }
    const int s0 = rowst[d], s1 = rowst[d + 1];
    for (int it = s0; it < s1; ++it) {
      const int s = csrc[it];
#pragma unroll
      for (int c = 0; c < 8; ++c) {
        const float4 hv = *(const float4*)&buf[swz(s, cb + c)];
        mx[c].x = fmaxf(mx[c].x, hv.x); mx[c].y = fmaxf(mx[c].y, hv.y);
        mx[c].z = fmaxf(mx[c].z, hv.z); mx[c].w = fmaxf(mx[c].w, hv.w);
      }
    }
    float sAp = 0.f;
#pragma unroll
    for (int c = 0; c < 8; ++c) {
      const float* uu = &u_[hh * 32 + c * 4];
      sAp += mx[c].x * uu[0] + mx[c].y * uu[1] + mx[c].z * uu[2] + mx[c].w * uu[3];
    }
    esc[tid] = sAp;          // tid == d*2+hh
    esc[1024 + tid] = sBp;
  }
  __syncthreads();
  if (tid < NPGL) {          // deterministic combine
    sA[tid] = c0s + esc[2 * tid] + esc[2 * tid + 1];
    sB[tid] = esc[1024 + 2 * tid] + esc[1024 + 2 * tid + 1];
  }
  __syncthreads();

  // ---------------- Phase 4: per-target softmax over edges ----------------
  if (tid < NPGL) {
    const int d = tid;
    const float sa = sA[d];
    float scS = sa + sB[d];
    scS = scS >= 0.f ? scS : 0.2f * scS;
    float mxv = scS;
    const int s0 = rowst[d], s1 = rowst[d + 1];
    for (int it = s0; it < s1; ++it) {
      float sc = sa + sB[csrc[it]];
      sc = sc >= 0.f ? sc : 0.2f * sc;
      mxv = fmaxf(mxv, sc);
    }
    const float esf = expf(scS - mxv);
    float sum = esf;
    for (int it = s0; it < s1; ++it) {
      float sc = sa + sB[csrc[it]];
      sc = sc >= 0.f ? sc : 0.2f * sc;
      const float e = expf(sc - mxv);
      esc[it] = e;
      sum += e;
    }
    eself[d] = esf;
    rsf[d] = 1.0f / (sum + 1e-16f);
  }
  __syncthreads();

  // ---------------- Phase 5: xnew = segsum(score * h1) (in-place) ----------------
  {
    const int d = tid >> 1, hh = tid & 1;
    const int cb = hh * 8;
    const float esf = eself[d];
    float4 acc[8];
#pragma unroll
    for (int c = 0; c < 8; ++c) {
      const float4 hv = *(const float4*)&buf[swz(d, cb + c)];
      acc[c].x = esf * hv.x; acc[c].y = esf * hv.y;
      acc[c].z = esf * hv.z; acc[c].w = esf * hv.w;
    }
    const int s0 = rowst[d], s1 = rowst[d + 1];
    for (int it = s0; it < s1; ++it) {
      const int s = csrc[it];
      const float e = esc[it];
#pragma unroll
      for (int c = 0; c < 8; ++c) {
        const float4 hv = *(const float4*)&buf[swz(s, cb + c)];
        acc[c].x += e * hv.x; acc[c].y += e * hv.y;
        acc[c].z += e * hv.z; acc[c].w += e * hv.w;
      }
    }
    const float r = rsf[d];
#pragma unroll
    for (int c = 0; c < 8; ++c) {
      acc[c].x *= r; acc[c].y *= r; acc[c].z *= r; acc[c].w *= r;
    }
    __syncthreads();
#pragma unroll
    for (int c = 0; c < 8; ++c) *(float4*)&buf[swz(d, cb + c)] = acc[c];
  }
  __syncthreads();

  // ---------------- Phase 6: LEConv fitness ----------------
  if (tid < NPGL) {
    const int n = tid;
    float av = 0.f, bv = 0.f, cv = 0.f;
    for (int c = 0; c < 16; ++c) {
      const float4 v = *(const float4*)&buf[swz(n, c)];
      const int k = c * 4;
      av += v.x * le1W[k] + v.y * le1W[k + 1] + v.z * le1W[k + 2] + v.w * le1W[k + 3];
      bv += v.x * le2W[k] + v.y * le2W[k + 1] + v.z * le2W[k + 2] + v.w * le2W[k + 3];
      cv += v.x * le3W[k] + v.y * le3W[k + 1] + v.z * le3W[k + 2] + v.w * le3W[k + 3];
    }
    sA[n] = av + le1b[0];     // a
    sB[n] = bv;               // b2_
    dinv_[n] = cv + le3b[0];  // lin3 term
  }
  __syncthreads();
  if (tid < NPGL) {
    const int d = tid;
    const int s0 = rowst[d], s1 = rowst[d + 1];
    float f = sA[d];                             // self-loop a
    for (int it = s0; it < s1; ++it) f += sA[csrc[it]];
    f -= (float)(s1 - s0 + 1) * sB[d];           // degF * b2_
    f += dinv_[d];
    float sg;
    if (f >= 0.f) sg = 1.f / (1.f + expf(-f));
    else { const float t = expf(f); sg = t / (1.f + t); }
    rsf[d] = sg;                                 // fitness
  }
  __syncthreads();

  // ---------------- Phase 7: top-K by rank (lax.top_k tie semantics) ----------------
  if (tid < NPGL) {
    const float fn = rsf[tid];
    int r = 0;
    for (int m = 0; m < NPGL; ++m) {
      const float fm = rsf[m];
      r += ((fm > fn) || (fm == fn && m < tid)) ? 1 : 0;
    }
    if (r < KKEEP) {
      const int p = atomicAdd(&kcount, 1);
      kept[p] = tid;
    }
  }
  __syncthreads();

  // ---------------- Phase 8: in-neighbor bitmasks (incl self) ----------------
  for (int i = tid; i < NPGL * 4; i += NTH) Imask[i] = 0ull;
  __syncthreads();
  if (tid < NPGL) atomicOr(&Imask[tid * 4 + (tid >> 6)], 1ull << (tid & 63));
#pragma unroll
  for (int i = 0; i < 4; ++i)
    atomicOr(&Imask[ed[i] * 4 + (es[i] >> 6)], 1ull << (es[i] & 63));
  __syncthreads();

  // ---------------- Phase 9: R[q] = union of I[m] over m in I[kept[q]] ----------------
  {
    const int q = tid >> 2, w = tid & 3;
    const int kq = kept[q];
    unsigned long long acc = 0ull;
#pragma unroll
    for (int ww = 0; ww < 4; ++ww) {
      unsigned long long bits = Imask[kq * 4 + ww];
      while (bits) {
        const int m = (ww << 6) + __builtin_ctzll(bits);
        bits &= bits - 1;
        acc |= Imask[m * 4 + w];
      }
    }
    Rmask[q * 4 + w] = acc;
  }
  __syncthreads();
  if (tid < KKEEP * 2) conn[tid] = 0ull;
  __syncthreads();
  {
    const int p = tid >> 2, wb = tid & 3;
    const int kp = kept[p];
    const unsigned long long I0 = Imask[kp * 4 + 0], I1 = Imask[kp * 4 + 1],
                             I2 = Imask[kp * 4 + 2], I3 = Imask[kp * 4 + 3];
    unsigned long long bits = 0ull;
    for (int j = 0; j < 32; ++j) {
      const int q = wb * 32 + j;
      if (q == p) continue;
      const unsigned long long* R = &Rmask[q * 4];
      if ((I0 & R[0]) | (I1 & R[1]) | (I2 & R[2]) | (I3 & R[3]))
        bits |= 1ull << (q & 63);
    }
    atomicOr(&conn[p * 2 + (wb >> 1)], bits);
  }
  __syncthreads();

  // ---------------- Phase 10: deg2, d2, c[s] ----------------
  if (tid < KKEEP) {
    const int q = tid;
    const int w = q >> 6;
    const unsigned long long bq = 1ull << (q & 63);
    int deg = 1;
    for (int p = 0; p < KKEEP; ++p) deg += (conn[p * 2 + w] & bq) ? 1 : 0;
    d2A[q] = rsqrtf((float)deg);
  }
  __syncthreads();
  if (tid < KKEEP) {
    const int s = tid;
    float acc = d2A[s];
#pragma unroll
    for (int w = 0; w < 2; ++w) {
      unsigned long long bits = conn[s * 2 + w];
      while (bits) {
        const int d = (w << 6) + __builtin_ctzll(bits);
        bits &= bits - 1;
        acc += d2A[d];
      }
    }
    cA[s] = d2A[s] * acc * rsf[kept[s]] * (1.0f / (float)KKEEP);
  }
  __syncthreads();

  // ---------------- Phase 11: wsum[k] = sum_s cA[s]*xnew[kept[s],k]; out ----------------
  {
    const int f = tid & 63, blk = tid >> 6;   // 8 blocks of 16 kept nodes
    float p = 0.f;
    for (int j = 0; j < 16; ++j) {
      const int s = blk * 16 + j;
      const int ks = kept[s];
      const int off = (ks << 6) + ((((f >> 2) ^ ks) & 15) << 2) + (f & 3);
      p += cA[s] * buf[off];
    }
    esc[blk * 64 + f] = p;
  }
  __syncthreads();
  if (tid < HIDD) {
    float s = 0.f;
#pragma unroll
    for (int b = 0; b < 8; ++b) s += esc[b * 64 + tid];
    wsum[tid] = s;
  }
  __syncthreads();
  if (tid < HIDD) {
    float o = b2[tid];
    for (int k = 0; k < HIDD; ++k) o += wsum[k] * W2[k * HIDD + tid];
    out[(size_t)g * HIDD + tid] = o;
  }
}

extern "C" void kernel_launch(void* const* d_in, const int* in_sizes, int n_in,
                              void* d_out, int out_size, void* d_ws, size_t ws_size,
                              hipStream_t stream) {
  (void)n_in; (void)out_size; (void)d_ws; (void)ws_size;
  const float* x    = (const float*)d_in[0];
  const int*   ei   = (const int*)d_in[1];
  // d_in[2] = batch (contiguous equal graphs; unused)
  const float* W1   = (const float*)d_in[3];
  const float* b1   = (const float*)d_in[4];
  const float* linW = (const float*)d_in[5];
  const float* linb = (const float*)d_in[6];
  const float* attW = (const float*)d_in[7];
  const float* attb = (const float*)d_in[8];
  const float* le1W = (const float*)d_in[9];
  const float* le1b = (const float*)d_in[10];
  const float* le2W = (const float*)d_in[11];
  const float* le3W = (const float*)d_in[12];
  const float* le3b = (const float*)d_in[13];
  const float* W2   = (const float*)d_in[14];
  const float* b2   = (const float*)d_in[15];
  const int Etot = in_sizes[1] / 2;   // 524288
  const int nGraphs = 256;

  asap_fused<<<dim3(nGraphs), dim3(NTH), 0, stream>>>(
      x, ei, W1, b1, linW, linb, attW, attb, le1W, le1b, le2W, le3W, le3b,
      W2, b2, (float*)d_out, Etot);
}

// Round 2
// 65.696 us; speedup vs baseline: 1.0652x; 1.0652x over previous
//
#include <hip/hip_runtime.h>

#define NPGL 256     // nodes per graph
#define EPGL 2048    // edges per graph
#define HIDD 64
#define KKEEP 128
#define NTH 1024

// float offset of float4-chunk c (0..15) of row n in the swizzled LDS tile
__device__ __forceinline__ int swz(int n, int c) {
  return (n << 6) + (((c ^ n) & 15) << 2);
}

__global__ void __launch_bounds__(NTH)
asap_fused(const float* __restrict__ x, const int* __restrict__ ei,
           const float* __restrict__ W1, const float* __restrict__ b1,
           const float* __restrict__ linW, const float* __restrict__ linb,
           const float* __restrict__ attW, const float* __restrict__ attb,
           const float* __restrict__ le1W, const float* __restrict__ le1b,
           const float* __restrict__ le2W,
           const float* __restrict__ le3W, const float* __restrict__ le3b,
           const float* __restrict__ W2, const float* __restrict__ b2,
           float* __restrict__ out, int Etot)
{
  const int g = blockIdx.x;
  const int tid = threadIdx.x;

  __shared__ __align__(16) float buf[NPGL * HIDD];   // 64KB: h -> h1 -> xnew
  __shared__ __align__(16) float w1s[HIDD * HIDD];   // 16KB: W1 -> scratch -> masks
  __shared__ unsigned short csrc[EPGL];              // 4KB CSR src (by dst)
  __shared__ int rowst[NPGL + 1];
  __shared__ int cnt[NPGL];
  __shared__ float dinv_[NPGL];                      // later: c3 per node
  __shared__ float sA[NPGL], sB[NPGL];               // later: a, bb per node
  __shared__ float eself[NPGL];
  __shared__ float rsf[NPGL];                        // recip softmax sum -> fitness
  __shared__ __align__(16) float esc[EPGL];          // 8KB: exp scores / partials
  __shared__ float u_[HIDD];
  __shared__ float wsum[HIDD];
  __shared__ int scanw[4];
  __shared__ float c0s;

  // aliases into w1s (W1 dead after phase 1; scratch dead before phase 8)
  unsigned long long* Imask = (unsigned long long*)w1s;           // [256*4]
  unsigned long long* Rmask = ((unsigned long long*)w1s) + 1024;  // [128*4]
  unsigned long long* conn  = ((unsigned long long*)w1s) + 1536;  // [128*2]
  int*   kept = (int*)(w1s + 3584);                               // [128]
  float* d2A  = w1s + 3712;                                       // [128]
  float* cA   = w1s + 3840;                                       // [128]

  const int ebase = g * EPGL;
  const int nbase = g * NPGL;

  // ---------------- Phase 0: CSR build (by dst) ----------------
  if (tid < NPGL) cnt[tid] = 0;
  __syncthreads();

  int es[2], ed[2];
#pragma unroll
  for (int i = 0; i < 2; ++i) {
    const int e = tid + i * NTH;
    es[i] = ei[ebase + e] - nbase;
    ed[i] = ei[Etot + ebase + e] - nbase;
    atomicAdd(&cnt[ed[i]], 1);
  }
  __syncthreads();

  int vscan = 0;
  if (tid < NPGL) {                 // wave-level inclusive scan over 256 counts
    vscan = cnt[tid];
#pragma unroll
    for (int off = 1; off < 64; off <<= 1) {
      const int up = __shfl_up(vscan, off, 64);
      if ((tid & 63) >= off) vscan += up;
    }
    if ((tid & 63) == 63) scanw[tid >> 6] = vscan;
  }
  __syncthreads();
  if (tid < NPGL) {
    int add = 0;
    const int w = tid >> 6;
    for (int ww = 0; ww < w; ++ww) add += scanw[ww];
    const int incl = vscan + add;
    rowst[tid + 1] = incl;
    cnt[tid] = incl - cnt[tid];     // exclusive scan = scatter cursor
    if (tid == 0) rowst[0] = 0;
  }
  __syncthreads();

#pragma unroll
  for (int i = 0; i < 2; ++i) {
    const int p = atomicAdd(&cnt[ed[i]], 1);
    csrc[p] = (unsigned short)es[i];
  }
  if (tid < NPGL) {
    const int len = rowst[tid + 1] - rowst[tid];
    dinv_[tid] = rsqrtf((float)len + 1.0f);       // conv1: +1 self loop
  }
  if (tid < HIDD) {                               // u = lin_W @ attW[:64]
    float a = 0.f;
    for (int f = 0; f < HIDD; ++f) a += linW[tid * HIDD + f] * attW[f];
    u_[tid] = a;
  }
  if (tid == 0) {
    float a = 0.f;
    for (int f = 0; f < HIDD; ++f) a += linb[f] * attW[f];
    c0s = a + attb[0];
  }
  ((float4*)w1s)[tid] = ((const float4*)W1)[tid];   // 1024 float4 = full W1
  __syncthreads();

  // ---------------- Phase 1: h = x @ W1 -> buf ----------------
  {
    const int d = tid >> 2;            // row
    const int qq = tid & 3;            // 16-feature block
    const float4* xg = (const float4*)(x + (size_t)(nbase + d) * HIDD);
    float4 a0[4];
#pragma unroll
    for (int c = 0; c < 4; ++c) a0[c] = make_float4(0.f, 0.f, 0.f, 0.f);
    for (int pass = 0; pass < 4; ++pass) {
      float4 xa[4];
#pragma unroll
      for (int c = 0; c < 4; ++c) xa[c] = xg[pass * 4 + c];
#pragma unroll
      for (int kk = 0; kk < 16; ++kk) {
        const int k = pass * 16 + kk;
        const float xv = ((const float*)xa)[kk];
        const float4* wr = (const float4*)&w1s[k * HIDD + qq * 16];
#pragma unroll
        for (int c = 0; c < 4; ++c) {
          const float4 w = wr[c];
          a0[c].x += xv * w.x; a0[c].y += xv * w.y;
          a0[c].z += xv * w.z; a0[c].w += xv * w.w;
        }
      }
    }
#pragma unroll
    for (int c = 0; c < 4; ++c) *(float4*)&buf[swz(d, qq * 4 + c)] = a0[c];
  }
  __syncthreads();

  // ---------------- Phase 2: h1 = relu(GCN agg) (in-place) ----------------
  {
    const int d = tid >> 2, hh = tid & 3;    // chunks hh, hh+4, hh+8, hh+12
    const float dd = dinv_[d];
    const float sc_ = dd * dd;
    float4 acc[4];
#pragma unroll
    for (int j = 0; j < 4; ++j) {
      const int c = hh + 4 * j;
      const float4 hv = *(const float4*)&buf[swz(d, c)];
      const float4 bv = *(const float4*)&b1[4 * c];
      acc[j].x = hv.x * sc_ + bv.x; acc[j].y = hv.y * sc_ + bv.y;
      acc[j].z = hv.z * sc_ + bv.z; acc[j].w = hv.w * sc_ + bv.w;
    }
    const int s0 = rowst[d], s1 = rowst[d + 1];
    for (int it = s0; it < s1; ++it) {
      const int s = csrc[it];
      const float cf = dinv_[s] * dd;
#pragma unroll
      for (int j = 0; j < 4; ++j) {
        const float4 hv = *(const float4*)&buf[swz(s, hh + 4 * j)];
        acc[j].x += cf * hv.x; acc[j].y += cf * hv.y;
        acc[j].z += cf * hv.z; acc[j].w += cf * hv.w;
      }
    }
#pragma unroll
    for (int j = 0; j < 4; ++j) {
      acc[j].x = fmaxf(acc[j].x, 0.f); acc[j].y = fmaxf(acc[j].y, 0.f);
      acc[j].z = fmaxf(acc[j].z, 0.f); acc[j].w = fmaxf(acc[j].w, 0.f);
    }
    __syncthreads();
#pragma unroll
    for (int j = 0; j < 4; ++j) *(float4*)&buf[swz(d, hh + 4 * j)] = acc[j];
  }
  __syncthreads();

  // ---------------- Phase 3: sA (segment-max dot u), sB ----------------
  {
    const int d = tid >> 2, hh = tid & 3;
    float4 mx[4];
    float sBp = 0.f;
#pragma unroll
    for (int j = 0; j < 4; ++j) {
      const int c = hh + 4 * j;
      const float4 hv = *(const float4*)&buf[swz(d, c)];
      mx[j] = hv;
      const float4 aw = *(const float4*)&attW[HIDD + 4 * c];
      sBp += hv.x * aw.x + hv.y * aw.y + hv.z * aw.z + hv.w * aw.w;
    }
    const int s0 = rowst[d], s1 = rowst[d + 1];
    for (int it = s0; it < s1; ++it) {
      const int s = csrc[it];
#pragma unroll
      for (int j = 0; j < 4; ++j) {
        const float4 hv = *(const float4*)&buf[swz(s, hh + 4 * j)];
        mx[j].x = fmaxf(mx[j].x, hv.x); mx[j].y = fmaxf(mx[j].y, hv.y);
        mx[j].z = fmaxf(mx[j].z, hv.z); mx[j].w = fmaxf(mx[j].w, hv.w);
      }
    }
    float sAp = 0.f;
#pragma unroll
    for (int j = 0; j < 4; ++j) {
      const float* uu = &u_[4 * (hh + 4 * j)];
      sAp += mx[j].x * uu[0] + mx[j].y * uu[1] + mx[j].z * uu[2] + mx[j].w * uu[3];
    }
    w1s[tid] = sAp;           // tid == d*4+hh
    w1s[1024 + tid] = sBp;
  }
  __syncthreads();
  if (tid < NPGL) {           // deterministic combine
    sA[tid] = c0s + ((w1s[4 * tid] + w1s[4 * tid + 1]) + (w1s[4 * tid + 2] + w1s[4 * tid + 3]));
    sB[tid] = ((w1s[1024 + 4 * tid] + w1s[1024 + 4 * tid + 1]) +
               (w1s[1024 + 4 * tid + 2] + w1s[1024 + 4 * tid + 3]));
  }
  __syncthreads();

  // ---------------- Phase 4: per-target softmax over edges ----------------
  if (tid < NPGL) {
    const int d = tid;
    const float sa = sA[d];
    float scS = sa + sB[d];
    scS = scS >= 0.f ? scS : 0.2f * scS;
    float mxv = scS;
    const int s0 = rowst[d], s1 = rowst[d + 1];
    for (int it = s0; it < s1; ++it) {
      float sc = sa + sB[csrc[it]];
      sc = sc >= 0.f ? sc : 0.2f * sc;
      mxv = fmaxf(mxv, sc);
    }
    const float esf = expf(scS - mxv);
    float sum = esf;
    for (int it = s0; it < s1; ++it) {
      float sc = sa + sB[csrc[it]];
      sc = sc >= 0.f ? sc : 0.2f * sc;
      const float e = expf(sc - mxv);
      esc[it] = e;
      sum += e;
    }
    eself[d] = esf;
    rsf[d] = 1.0f / (sum + 1e-16f);
  }
  __syncthreads();

  // ---------------- Phase 5: xnew = segsum(score * h1) (in-place) ----------------
  {
    const int d = tid >> 2, hh = tid & 3;
    const float esf = eself[d];
    float4 acc[4];
#pragma unroll
    for (int j = 0; j < 4; ++j) {
      const float4 hv = *(const float4*)&buf[swz(d, hh + 4 * j)];
      acc[j].x = esf * hv.x; acc[j].y = esf * hv.y;
      acc[j].z = esf * hv.z; acc[j].w = esf * hv.w;
    }
    const int s0 = rowst[d], s1 = rowst[d + 1];
    for (int it = s0; it < s1; ++it) {
      const int s = csrc[it];
      const float e = esc[it];
#pragma unroll
      for (int j = 0; j < 4; ++j) {
        const float4 hv = *(const float4*)&buf[swz(s, hh + 4 * j)];
        acc[j].x += e * hv.x; acc[j].y += e * hv.y;
        acc[j].z += e * hv.z; acc[j].w += e * hv.w;
      }
    }
    const float r = rsf[d];
#pragma unroll
    for (int j = 0; j < 4; ++j) {
      acc[j].x *= r; acc[j].y *= r; acc[j].z *= r; acc[j].w *= r;
    }
    __syncthreads();
#pragma unroll
    for (int j = 0; j < 4; ++j) *(float4*)&buf[swz(d, hh + 4 * j)] = acc[j];
  }
  __syncthreads();

  // ---------------- Phase 6: LEConv fitness ----------------
  if (tid < NPGL) {
    const int n = tid;
    float av = 0.f, bv = 0.f, cv = 0.f;
    for (int c = 0; c < 16; ++c) {
      const float4 v = *(const float4*)&buf[swz(n, c)];
      const int k = c * 4;
      av += v.x * le1W[k] + v.y * le1W[k + 1] + v.z * le1W[k + 2] + v.w * le1W[k + 3];
      bv += v.x * le2W[k] + v.y * le2W[k + 1] + v.z * le2W[k + 2] + v.w * le2W[k + 3];
      cv += v.x * le3W[k] + v.y * le3W[k + 1] + v.z * le3W[k + 2] + v.w * le3W[k + 3];
    }
    sA[n] = av + le1b[0];     // a
    sB[n] = bv;               // b2_
    dinv_[n] = cv + le3b[0];  // lin3 term
  }
  __syncthreads();
  if (tid < NPGL) {
    const int d = tid;
    const int s0 = rowst[d], s1 = rowst[d + 1];
    float f = sA[d];                             // self-loop a
    for (int it = s0; it < s1; ++it) f += sA[csrc[it]];
    f -= (float)(s1 - s0 + 1) * sB[d];           // degF * b2_
    f += dinv_[d];
    float sg;
    if (f >= 0.f) sg = 1.f / (1.f + expf(-f));
    else { const float t = expf(f); sg = t / (1.f + t); }
    rsf[d] = sg;                                 // fitness
  }
  __syncthreads();

  // ---------------- Phase 7: top-K by rank (lax.top_k tie semantics) ----------------
  if (tid < NPGL) {
    const float fn = rsf[tid];
    int r = 0;
    for (int m = 0; m < NPGL; ++m) {
      const float fm = rsf[m];
      r += ((fm > fn) || (fm == fn && m < tid)) ? 1 : 0;
    }
    if (r < KKEEP) kept[r] = tid;   // unique rank -> deterministic, no atomic
  }
  __syncthreads();

  // ---------------- Phase 8: in-neighbor bitmasks (incl self) ----------------
  if (tid < NPGL * 4) Imask[tid] = 0ull;
  __syncthreads();
  if (tid < NPGL) atomicOr(&Imask[tid * 4 + (tid >> 6)], 1ull << (tid & 63));
#pragma unroll
  for (int i = 0; i < 2; ++i)
    atomicOr(&Imask[ed[i] * 4 + (es[i] >> 6)], 1ull << (es[i] & 63));
  __syncthreads();

  // ---------------- Phase 9: R[q] = union of I[m] over m in I[kept[q]] ----------------
  if (tid < KKEEP * 4) {
    const int q = tid >> 2, w = tid & 3;
    const int kq = kept[q];
    unsigned long long acc = 0ull;
#pragma unroll
    for (int ww = 0; ww < 4; ++ww) {
      unsigned long long bits = Imask[kq * 4 + ww];
      while (bits) {
        const int m = (ww << 6) + __builtin_ctzll(bits);
        bits &= bits - 1;
        acc |= Imask[m * 4 + w];
      }
    }
    Rmask[q * 4 + w] = acc;
  }
  __syncthreads();
  if (tid < KKEEP * 2) conn[tid] = 0ull;
  __syncthreads();
  if (tid < KKEEP * 4) {
    const int p = tid >> 2, wb = tid & 3;
    const int kp = kept[p];
    const unsigned long long I0 = Imask[kp * 4 + 0], I1 = Imask[kp * 4 + 1],
                             I2 = Imask[kp * 4 + 2], I3 = Imask[kp * 4 + 3];
    unsigned long long bits = 0ull;
    for (int j = 0; j < 32; ++j) {
      const int q = wb * 32 + j;
      if (q == p) continue;
      const unsigned long long* R = &Rmask[q * 4];
      if ((I0 & R[0]) | (I1 & R[1]) | (I2 & R[2]) | (I3 & R[3]))
        bits |= 1ull << (q & 63);
    }
    atomicOr(&conn[p * 2 + (wb >> 1)], bits);
  }
  __syncthreads();

  // ---------------- Phase 10: deg2, d2, c[s] ----------------
  if (tid < KKEEP) {
    const int q = tid;
    const int w = q >> 6;
    const unsigned long long bq = 1ull << (q & 63);
    int deg = 1;
    for (int p = 0; p < KKEEP; ++p) deg += (conn[p * 2 + w] & bq) ? 1 : 0;
    d2A[q] = rsqrtf((float)deg);
  }
  __syncthreads();
  if (tid < KKEEP) {
    const int s = tid;
    float acc = d2A[s];
#pragma unroll
    for (int w = 0; w < 2; ++w) {
      unsigned long long bits = conn[s * 2 + w];
      while (bits) {
        const int d = (w << 6) + __builtin_ctzll(bits);
        bits &= bits - 1;
        acc += d2A[d];
      }
    }
    cA[s] = d2A[s] * acc * rsf[kept[s]] * (1.0f / (float)KKEEP);
  }
  __syncthreads();

  // ---------------- Phase 11: wsum[k] = sum_s cA[s]*xnew[kept[s],k]; out ----------------
  {
    const int f = tid & 63, blk = tid >> 6;   // 16 blocks of 8 kept nodes
    float p = 0.f;
    for (int j = 0; j < 8; ++j) {
      const int s = blk * 8 + j;
      const int ks = kept[s];
      const int off = (ks << 6) + ((((f >> 2) ^ ks) & 15) << 2) + (f & 3);
      p += cA[s] * buf[off];
    }
    esc[blk * 64 + f] = p;
  }
  __syncthreads();
  if (tid < HIDD) {
    float s = 0.f;
#pragma unroll
    for (int b = 0; b < 16; ++b) s += esc[b * 64 + tid];
    wsum[tid] = s;
  }
  __syncthreads();
  if (tid < HIDD) {
    float o = b2[tid];
    for (int k = 0; k < HIDD; ++k) o += wsum[k] * W2[k * HIDD + tid];
    out[(size_t)g * HIDD + tid] = o;
  }
}

extern "C" void kernel_launch(void* const* d_in, const int* in_sizes, int n_in,
                              void* d_out, int out_size, void* d_ws, size_t ws_size,
                              hipStream_t stream) {
  (void)n_in; (void)out_size; (void)d_ws; (void)ws_size;
  const float* x    = (const float*)d_in[0];
  const int*   ei   = (const int*)d_in[1];
  // d_in[2] = batch (contiguous equal graphs; unused)
  const float* W1   = (const float*)d_in[3];
  const float* b1   = (const float*)d_in[4];
  const float* linW = (const float*)d_in[5];
  const float* linb = (const float*)d_in[6];
  const float* attW = (const float*)d_in[7];
  const float* attb = (const float*)d_in[8];
  const float* le1W = (const float*)d_in[9];
  const float* le1b = (const float*)d_in[10];
  const float* le2W = (const float*)d_in[11];
  const float* le3W = (const float*)d_in[12];
  const float* le3b = (const float*)d_in[13];
  const float* W2   = (const float*)d_in[14];
  const float* b2   = (const float*)d_in[15];
  const int Etot = in_sizes[1] / 2;   // 524288
  const int nGraphs = 256;

  asap_fused<<<dim3(nGraphs), dim3(NTH), 0, stream>>>(
      x, ei, W1, b1, linW, linb, attW, attb, le1W, le1b, le2W, le3W, le3b,
      W2, b2, (float*)d_out, Etot);
}

// Round 3
// 58.204 us; speedup vs baseline: 1.2024x; 1.1287x over previous
//
#include <hip/hip_runtime.h>

#define NPGL 256     // nodes per graph
#define EPGL 2048    // edges per graph
#define HIDD 64
#define KKEEP 128
#define NTH 1024

// float offset of float4-chunk c (0..15) of row n in the swizzled LDS tile.
// XOR by n and n>>4 so both row-gathers (fixed n, varying c) and
// column-reads (fixed c, varying n) spread across bank groups.
__device__ __forceinline__ int swz(int n, int c) {
  return (n << 6) + ((((c ^ n) ^ (n >> 4)) & 15) << 2);
}

__global__ void __launch_bounds__(NTH)
asap_fused(const float* __restrict__ x, const int* __restrict__ ei,
           const float* __restrict__ W1, const float* __restrict__ b1,
           const float* __restrict__ linW, const float* __restrict__ linb,
           const float* __restrict__ attW, const float* __restrict__ attb,
           const float* __restrict__ le1W, const float* __restrict__ le1b,
           const float* __restrict__ le2W,
           const float* __restrict__ le3W, const float* __restrict__ le3b,
           const float* __restrict__ W2, const float* __restrict__ b2,
           float* __restrict__ out, int Etot)
{
  const int g = blockIdx.x;
  const int tid = threadIdx.x;

  __shared__ __align__(16) float buf[NPGL * HIDD];   // 64KB: x -> h -> h1 -> xnew
  __shared__ __align__(16) float mskf[4096];         // 16KB: bitmask phase scratch
  __shared__ unsigned short csrc[EPGL];              // 4KB CSR src (by dst)
  __shared__ int rowst[NPGL + 1];
  __shared__ int cnt[NPGL];
  __shared__ float dinv_[NPGL];                      // later: c3 per node
  __shared__ float sA[NPGL], sB[NPGL];               // later: a, bb per node
  __shared__ float eself[NPGL];
  __shared__ float rsf[NPGL];                        // recip softmax sum -> fitness
  __shared__ __align__(16) float esc[EPGL];          // 8KB: exp scores / partials
  __shared__ float u_[HIDD];
  __shared__ float wsum[HIDD];
  __shared__ int scanw[4];
  __shared__ float c0s;

  // aliases into mskf
  unsigned long long* Imask = (unsigned long long*)mskf;           // [256*4]
  unsigned long long* Rmask = ((unsigned long long*)mskf) + 1024;  // [128*4]
  unsigned long long* conn  = ((unsigned long long*)mskf) + 1536;  // [128*2]
  int*   kept = (int*)(mskf + 3584);                               // [128]
  float* d2A  = mskf + 3712;                                       // [128]
  float* cA   = mskf + 3840;                                       // [128]

  const int ebase = g * EPGL;
  const int nbase = g * NPGL;

  // ---------------- Phase 0: CSR build (by dst) + x staging ----------------
  if (tid < NPGL) cnt[tid] = 0;
  __syncthreads();

  int es[2], ed[2];
#pragma unroll
  for (int i = 0; i < 2; ++i) {
    const int e = tid + i * NTH;
    es[i] = ei[ebase + e] - nbase;
    ed[i] = ei[Etot + ebase + e] - nbase;
    atomicAdd(&cnt[ed[i]], 1);
  }

  // stage x into buf (swizzled) while counts settle? need cnt done first -> after.
  __syncthreads();

  int vscan = 0;
  if (tid < NPGL) {                 // wave-level inclusive scan over 256 counts
    vscan = cnt[tid];
#pragma unroll
    for (int off = 1; off < 64; off <<= 1) {
      const int up = __shfl_up(vscan, off, 64);
      if ((tid & 63) >= off) vscan += up;
    }
    if ((tid & 63) == 63) scanw[tid >> 6] = vscan;
  }
  __syncthreads();
  if (tid < NPGL) {
    int add = 0;
    const int w = tid >> 6;
    for (int ww = 0; ww < w; ++ww) add += scanw[ww];
    const int incl = vscan + add;
    rowst[tid + 1] = incl;
    cnt[tid] = incl - cnt[tid];     // exclusive scan = scatter cursor
    if (tid == 0) rowst[0] = 0;
  }
  __syncthreads();

#pragma unroll
  for (int i = 0; i < 2; ++i) {
    const int p = atomicAdd(&cnt[ed[i]], 1);
    csrc[p] = (unsigned short)es[i];
  }
  if (tid < NPGL) {
    const int len = rowst[tid + 1] - rowst[tid];
    dinv_[tid] = rsqrtf((float)len + 1.0f);       // conv1: +1 self loop
  }
  if (tid < HIDD) {                               // u = lin_W @ attW[:64]
    float a = 0.f;
    for (int f = 0; f < HIDD; ++f) a += linW[tid * HIDD + f] * attW[f];
    u_[tid] = a;
  }
  if (tid == 0) {
    float a = 0.f;
    for (int f = 0; f < HIDD; ++f) a += linb[f] * attW[f];
    c0s = a + attb[0];
  }
  // stage x -> buf (swizzled)
  {
    const float4* xg = (const float4*)(x + (size_t)nbase * HIDD);
#pragma unroll
    for (int ii = 0; ii < 4; ++ii) {
      const int i = tid + ii * NTH;
      const int r = i >> 4, c = i & 15;
      *(float4*)&buf[swz(r, c)] = xg[i];
    }
  }
  __syncthreads();

  // ---------------- Phase 1: h = x @ W1 (W1 via scalar loads) ----------------
  {
    const int wv = tid >> 6;                 // 0..15
    const int r  = ((wv & 3) << 6) + (tid & 63);   // row (wave-uniform group)
    const int fc = __builtin_amdgcn_readfirstlane(wv >> 2);  // 16-feature chunk
    const float* __restrict__ Wg = W1 + fc * 16;   // scalar base
    float4 acc[4];
#pragma unroll
    for (int c = 0; c < 4; ++c) acc[c] = make_float4(0.f, 0.f, 0.f, 0.f);
#pragma unroll
    for (int p = 0; p < 4; ++p) {
      float4 xa[4];
#pragma unroll
      for (int c = 0; c < 4; ++c) xa[c] = *(const float4*)&buf[swz(r, p * 4 + c)];
#pragma unroll
      for (int kk = 0; kk < 16; ++kk) {
        const int k = p * 16 + kk;
        const float xv = ((const float*)xa)[kk];
        const float* __restrict__ Wk = Wg + k * HIDD;  // uniform -> s_load
#pragma unroll
        for (int c = 0; c < 4; ++c) {
          const float4 w = *(const float4*)(Wk + c * 4);
          acc[c].x += xv * w.x; acc[c].y += xv * w.y;
          acc[c].z += xv * w.z; acc[c].w += xv * w.w;
        }
      }
    }
    __syncthreads();                // all x reads done before h overwrite
#pragma unroll
    for (int c = 0; c < 4; ++c) *(float4*)&buf[swz(r, fc * 4 + c)] = acc[c];
  }
  __syncthreads();

  // ---------------- Phase 2: h1 = relu(GCN agg) (in-place) ----------------
  {
    const int d = tid >> 2, hh = tid & 3;    // chunks hh, hh+4, hh+8, hh+12
    const float dd = dinv_[d];
    const float sc_ = dd * dd;
    float4 acc[4];
#pragma unroll
    for (int j = 0; j < 4; ++j) {
      const int c = hh + 4 * j;
      const float4 hv = *(const float4*)&buf[swz(d, c)];
      const float4 bv = *(const float4*)&b1[4 * c];
      acc[j].x = hv.x * sc_ + bv.x; acc[j].y = hv.y * sc_ + bv.y;
      acc[j].z = hv.z * sc_ + bv.z; acc[j].w = hv.w * sc_ + bv.w;
    }
    const int s0 = rowst[d], s1 = rowst[d + 1];
    int it = s0;
    for (; it + 2 <= s1; it += 2) {
      const int sa_ = csrc[it], sb_ = csrc[it + 1];
      const float ca_ = dinv_[sa_] * dd, cb_ = dinv_[sb_] * dd;
#pragma unroll
      for (int j = 0; j < 4; ++j) {
        const float4 ha = *(const float4*)&buf[swz(sa_, hh + 4 * j)];
        const float4 hb = *(const float4*)&buf[swz(sb_, hh + 4 * j)];
        acc[j].x += ca_ * ha.x + cb_ * hb.x;
        acc[j].y += ca_ * ha.y + cb_ * hb.y;
        acc[j].z += ca_ * ha.z + cb_ * hb.z;
        acc[j].w += ca_ * ha.w + cb_ * hb.w;
      }
    }
    if (it < s1) {
      const int s = csrc[it];
      const float cf = dinv_[s] * dd;
#pragma unroll
      for (int j = 0; j < 4; ++j) {
        const float4 hv = *(const float4*)&buf[swz(s, hh + 4 * j)];
        acc[j].x += cf * hv.x; acc[j].y += cf * hv.y;
        acc[j].z += cf * hv.z; acc[j].w += cf * hv.w;
      }
    }
#pragma unroll
    for (int j = 0; j < 4; ++j) {
      acc[j].x = fmaxf(acc[j].x, 0.f); acc[j].y = fmaxf(acc[j].y, 0.f);
      acc[j].z = fmaxf(acc[j].z, 0.f); acc[j].w = fmaxf(acc[j].w, 0.f);
    }
    __syncthreads();
#pragma unroll
    for (int j = 0; j < 4; ++j) *(float4*)&buf[swz(d, hh + 4 * j)] = acc[j];
  }
  __syncthreads();

  // ---------------- Phase 3: sA (segment-max dot u), sB ----------------
  {
    const int d = tid >> 2, hh = tid & 3;
    float4 mx[4];
    float sBp = 0.f;
#pragma unroll
    for (int j = 0; j < 4; ++j) {
      const int c = hh + 4 * j;
      const float4 hv = *(const float4*)&buf[swz(d, c)];
      mx[j] = hv;
      const float4 aw = *(const float4*)&attW[HIDD + 4 * c];
      sBp += hv.x * aw.x + hv.y * aw.y + hv.z * aw.z + hv.w * aw.w;
    }
    const int s0 = rowst[d], s1 = rowst[d + 1];
    int it = s0;
    for (; it + 2 <= s1; it += 2) {
      const int sa_ = csrc[it], sb_ = csrc[it + 1];
#pragma unroll
      for (int j = 0; j < 4; ++j) {
        const float4 ha = *(const float4*)&buf[swz(sa_, hh + 4 * j)];
        const float4 hb = *(const float4*)&buf[swz(sb_, hh + 4 * j)];
        mx[j].x = fmaxf(mx[j].x, fmaxf(ha.x, hb.x));
        mx[j].y = fmaxf(mx[j].y, fmaxf(ha.y, hb.y));
        mx[j].z = fmaxf(mx[j].z, fmaxf(ha.z, hb.z));
        mx[j].w = fmaxf(mx[j].w, fmaxf(ha.w, hb.w));
      }
    }
    if (it < s1) {
      const int s = csrc[it];
#pragma unroll
      for (int j = 0; j < 4; ++j) {
        const float4 hv = *(const float4*)&buf[swz(s, hh + 4 * j)];
        mx[j].x = fmaxf(mx[j].x, hv.x); mx[j].y = fmaxf(mx[j].y, hv.y);
        mx[j].z = fmaxf(mx[j].z, hv.z); mx[j].w = fmaxf(mx[j].w, hv.w);
      }
    }
    float sAp = 0.f;
#pragma unroll
    for (int j = 0; j < 4; ++j) {
      const float* uu = &u_[4 * (hh + 4 * j)];
      sAp += mx[j].x * uu[0] + mx[j].y * uu[1] + mx[j].z * uu[2] + mx[j].w * uu[3];
    }
    // deterministic quad combine: ((p0+p1)+(p2+p3))
    sAp += __shfl_xor(sAp, 1); sAp += __shfl_xor(sAp, 2);
    sBp += __shfl_xor(sBp, 1); sBp += __shfl_xor(sBp, 2);
    if (hh == 0) { sA[d] = c0s + sAp; sB[d] = sBp; }
  }
  __syncthreads();

  // ---------------- Phase 4: per-target softmax (4 lanes/dst) ----------------
  {
    const int d = tid >> 2, q = tid & 3;
    const float sa = sA[d];
    const int s0 = rowst[d], s1 = rowst[d + 1];
    float scS = sa + sB[d];
    scS = scS >= 0.f ? scS : 0.2f * scS;
    float mxv = scS;
    for (int it = s0 + q; it < s1; it += 4) {
      float sc = sa + sB[csrc[it]];
      sc = sc >= 0.f ? sc : 0.2f * sc;
      mxv = fmaxf(mxv, sc);
    }
    mxv = fmaxf(mxv, __shfl_xor(mxv, 1));
    mxv = fmaxf(mxv, __shfl_xor(mxv, 2));
    float sum = 0.f;
    for (int it = s0 + q; it < s1; it += 4) {
      float sc = sa + sB[csrc[it]];
      sc = sc >= 0.f ? sc : 0.2f * sc;
      const float e = __expf(sc - mxv);
      esc[it] = e;
      sum += e;
    }
    sum += __shfl_xor(sum, 1); sum += __shfl_xor(sum, 2);
    const float esf = __expf(scS - mxv);
    if (q == 0) {
      eself[d] = esf;
      rsf[d] = 1.0f / (esf + sum + 1e-16f);
    }
  }
  __syncthreads();

  // ---------------- Phase 5: xnew = segsum(score * h1) (in-place) ----------------
  {
    const int d = tid >> 2, hh = tid & 3;
    const float esf = eself[d];
    float4 acc[4];
#pragma unroll
    for (int j = 0; j < 4; ++j) {
      const float4 hv = *(const float4*)&buf[swz(d, hh + 4 * j)];
      acc[j].x = esf * hv.x; acc[j].y = esf * hv.y;
      acc[j].z = esf * hv.z; acc[j].w = esf * hv.w;
    }
    const int s0 = rowst[d], s1 = rowst[d + 1];
    int it = s0;
    for (; it + 2 <= s1; it += 2) {
      const int sa_ = csrc[it], sb_ = csrc[it + 1];
      const float ea = esc[it], eb = esc[it + 1];
#pragma unroll
      for (int j = 0; j < 4; ++j) {
        const float4 ha = *(const float4*)&buf[swz(sa_, hh + 4 * j)];
        const float4 hb = *(const float4*)&buf[swz(sb_, hh + 4 * j)];
        acc[j].x += ea * ha.x + eb * hb.x;
        acc[j].y += ea * ha.y + eb * hb.y;
        acc[j].z += ea * ha.z + eb * hb.z;
        acc[j].w += ea * ha.w + eb * hb.w;
      }
    }
    if (it < s1) {
      const int s = csrc[it];
      const float e = esc[it];
#pragma unroll
      for (int j = 0; j < 4; ++j) {
        const float4 hv = *(const float4*)&buf[swz(s, hh + 4 * j)];
        acc[j].x += e * hv.x; acc[j].y += e * hv.y;
        acc[j].z += e * hv.z; acc[j].w += e * hv.w;
      }
    }
    const float r = rsf[d];
#pragma unroll
    for (int j = 0; j < 4; ++j) {
      acc[j].x *= r; acc[j].y *= r; acc[j].z *= r; acc[j].w *= r;
    }
    __syncthreads();
#pragma unroll
    for (int j = 0; j < 4; ++j) *(float4*)&buf[swz(d, hh + 4 * j)] = acc[j];
  }
  __syncthreads();

  // ---------------- Phase 6: LEConv fitness (4 lanes/node) ----------------
  {
    const int n = tid >> 2, q = tid & 3;
    float av = 0.f, bv = 0.f, cv = 0.f;
#pragma unroll
    for (int j = 0; j < 4; ++j) {
      const int c = q + 4 * j;
      const float4 v = *(const float4*)&buf[swz(n, c)];
      const int k = c * 4;
      av += v.x * le1W[k] + v.y * le1W[k + 1] + v.z * le1W[k + 2] + v.w * le1W[k + 3];
      bv += v.x * le2W[k] + v.y * le2W[k + 1] + v.z * le2W[k + 2] + v.w * le2W[k + 3];
      cv += v.x * le3W[k] + v.y * le3W[k + 1] + v.z * le3W[k + 2] + v.w * le3W[k + 3];
    }
    av += __shfl_xor(av, 1); av += __shfl_xor(av, 2);
    bv += __shfl_xor(bv, 1); bv += __shfl_xor(bv, 2);
    cv += __shfl_xor(cv, 1); cv += __shfl_xor(cv, 2);
    if (q == 0) {
      sA[n] = av + le1b[0];     // a
      sB[n] = bv;               // b2_
      dinv_[n] = cv + le3b[0];  // lin3 term
    }
  }
  __syncthreads();
  {
    const int d = tid >> 2, q = tid & 3;
    const int s0 = rowst[d], s1 = rowst[d + 1];
    float fp = 0.f;
    for (int it = s0 + q; it < s1; it += 4) fp += sA[csrc[it]];
    fp += __shfl_xor(fp, 1); fp += __shfl_xor(fp, 2);
    if (q == 0) {
      float f = sA[d] + fp;                        // self-loop a + edge sum
      f -= (float)(s1 - s0 + 1) * sB[d];           // degF * b2_
      f += dinv_[d];
      float sg;
      if (f >= 0.f) sg = 1.f / (1.f + expf(-f));
      else { const float t = expf(f); sg = t / (1.f + t); }
      rsf[d] = sg;                                 // fitness
    }
  }
  __syncthreads();

  // ---------------- Phase 7: top-K by rank (4 lanes/node) ----------------
  {
    const int n = tid >> 2, q = tid & 3;
    const float fn = rsf[n];
    int r = 0;
    for (int m = q * 64; m < q * 64 + 64; ++m) {
      const float fm = rsf[m];
      r += ((fm > fn) || (fm == fn && m < n)) ? 1 : 0;
    }
    r += __shfl_xor(r, 1); r += __shfl_xor(r, 2);
    if (q == 0 && r < KKEEP) kept[r] = n;   // unique rank -> deterministic
  }
  __syncthreads();

  // ---------------- Phase 8: in-neighbor bitmasks (incl self) ----------------
  Imask[tid] = 0ull;
  __syncthreads();
  if (tid < NPGL) atomicOr(&Imask[tid * 4 + (tid >> 6)], 1ull << (tid & 63));
#pragma unroll
  for (int i = 0; i < 2; ++i)
    atomicOr(&Imask[ed[i] * 4 + (es[i] >> 6)], 1ull << (es[i] & 63));
  __syncthreads();

  // ---------------- Phase 9: R[q] = union of I[m] over m in I[kept[q]] ----------------
  if (tid < KKEEP * 4) {
    const int q = tid >> 2, w = tid & 3;
    const int kq = kept[q];
    unsigned long long acc = 0ull;
#pragma unroll
    for (int ww = 0; ww < 4; ++ww) {
      unsigned long long bits = Imask[kq * 4 + ww];
      while (bits) {
        const int m = (ww << 6) + __builtin_ctzll(bits);
        bits &= bits - 1;
        acc |= Imask[m * 4 + w];
      }
    }
    Rmask[q * 4 + w] = acc;
  }
  __syncthreads();
  if (tid < KKEEP * 2) conn[tid] = 0ull;
  __syncthreads();
  if (tid < KKEEP * 4) {
    const int p = tid >> 2, wb = tid & 3;
    const int kp = kept[p];
    const unsigned long long I0 = Imask[kp * 4 + 0], I1 = Imask[kp * 4 + 1],
                             I2 = Imask[kp * 4 + 2], I3 = Imask[kp * 4 + 3];
    unsigned long long bits = 0ull;
    for (int j = 0; j < 32; ++j) {
      const int q = wb * 32 + j;
      if (q == p) continue;
      const unsigned long long* R = &Rmask[q * 4];
      if ((I0 & R[0]) | (I1 & R[1]) | (I2 & R[2]) | (I3 & R[3]))
        bits |= 1ull << (q & 63);
    }
    atomicOr(&conn[p * 2 + (wb >> 1)], bits);
  }
  __syncthreads();

  // ---------------- Phase 10: deg2, d2, c[s] ----------------
  if (tid < KKEEP) {
    const int q = tid;
    const int w = q >> 6;
    const unsigned long long bq = 1ull << (q & 63);
    int deg = 1;
    for (int p = 0; p < KKEEP; ++p) deg += (conn[p * 2 + w] & bq) ? 1 : 0;
    d2A[q] = rsqrtf((float)deg);
  }
  __syncthreads();
  if (tid < KKEEP) {
    const int s = tid;
    float acc = d2A[s];
#pragma unroll
    for (int w = 0; w < 2; ++w) {
      unsigned long long bits = conn[s * 2 + w];
      while (bits) {
        const int d = (w << 6) + __builtin_ctzll(bits);
        bits &= bits - 1;
        acc += d2A[d];
      }
    }
    cA[s] = d2A[s] * acc * rsf[kept[s]] * (1.0f / (float)KKEEP);
  }
  __syncthreads();

  // ---------------- Phase 11: wsum[k] = sum_s cA[s]*xnew[kept[s],k]; out ----------------
  {
    const int f = tid & 63, blk = tid >> 6;   // 16 blocks of 8 kept nodes
    float p = 0.f;
    for (int j = 0; j < 8; ++j) {
      const int s = blk * 8 + j;
      const int ks = kept[s];
      const int off = (ks << 6) + (((((f >> 2) ^ ks) ^ (ks >> 4)) & 15) << 2) + (f & 3);
      p += cA[s] * buf[off];
    }
    esc[blk * 64 + f] = p;
  }
  __syncthreads();
  if (tid < HIDD) {
    float s = 0.f;
#pragma unroll
    for (int b = 0; b < 16; ++b) s += esc[b * 64 + tid];
    wsum[tid] = s;
  }
  __syncthreads();
  if (tid < HIDD) {
    float o = b2[tid];
    for (int k = 0; k < HIDD; ++k) o += wsum[k] * W2[k * HIDD + tid];
    out[(size_t)g * HIDD + tid] = o;
  }
}

extern "C" void kernel_launch(void* const* d_in, const int* in_sizes, int n_in,
                              void* d_out, int out_size, void* d_ws, size_t ws_size,
                              hipStream_t stream) {
  (void)n_in; (void)out_size; (void)d_ws; (void)ws_size;
  const float* x    = (const float*)d_in[0];
  const int*   ei   = (const int*)d_in[1];
  // d_in[2] = batch (contiguous equal graphs; unused)
  const float* W1   = (const float*)d_in[3];
  const float* b1   = (const float*)d_in[4];
  const float* linW = (const float*)d_in[5];
  const float* linb = (const float*)d_in[6];
  const float* attW = (const float*)d_in[7];
  const float* attb = (const float*)d_in[8];
  const float* le1W = (const float*)d_in[9];
  const float* le1b = (const float*)d_in[10];
  const float* le2W = (const float*)d_in[11];
  const float* le3W = (const float*)d_in[12];
  const float* le3b = (const float*)d_in[13];
  const float* W2   = (const float*)d_in[14];
  const float* b2   = (const float*)d_in[15];
  const int Etot = in_sizes[1] / 2;   // 524288
  const int nGraphs = 256;

  asap_fused<<<dim3(nGraphs), dim3(NTH), 0, stream>>>(
      x, ei, W1, b1, linW, linb, attW, attb, le1W, le1b, le2W, le3W, le3b,
      W2, b2, (float*)d_out, Etot);
}